// Round 14
// baseline (421.727 us; speedup 1.0000x reference)
//
#include <hip/hip_runtime.h>
#include <hip/hip_bf16.h>

typedef __hip_bfloat16 bf16;
typedef short s16x8 __attribute__((ext_vector_type(8)));
typedef float f32x4 __attribute__((ext_vector_type(4)));

#define MFMA16(a, b, c) __builtin_amdgcn_mfma_f32_16x16x32_bf16(a, b, c, 0, 0, 0)
#define SCALE 0.125f
// exp(x*SCALE) == exp2(x * SCALE*log2(e)); folded into the Q store.
#define SCALE_LOG2E 0.18033688011112042f

typedef __attribute__((address_space(1))) void gvoid;
typedef __attribute__((address_space(3))) void lvoid;

static __device__ __forceinline__ void lds_cp16(const bf16* g, bf16* l) {
    // async global->LDS, 16B per lane; LDS dest = wave-uniform base + lane*16
    __builtin_amdgcn_global_load_lds((gvoid*)g, (lvoid*)l, 16, 0, 0);
}

// Bank-conflict swizzle for [rows][32] bf16 GEMM tiles (rule #21: both-sides).
// LDS slot s (16B chunks; row = s>>2, chunk = s&3) holds GLOBAL chunk
// (s&3) ^ ((s>>3)&3). Reads XOR the same key: phys chunk = lq ^ ((lm>>1)&3).
static __device__ __forceinline__ size_t swz_gofs(int slot, int K) {
    return (size_t)(slot >> 2) * K + (((slot & 3) ^ ((slot >> 3) & 3)) * 8);
}

// ---------------------------------------------------------------------------
// One fused prep pass: q_in/k_in f32->bf16, rope, biases, and the three
// weight transposes. Blocks: [0,4096) q, [4096,8192) k, [8192,8256) rope,
// 8256 bq/bp, 8257 bkv, [8258, 8258+4096) transpose (128 x 32 tiles).
// ---------------------------------------------------------------------------
static __device__ __forceinline__ void cast8(const float* src, bf16* dst,
                                             int i) {
    float4 a = *(const float4*)(src + i);
    float4 b = *(const float4*)(src + i + 4);
    bf16 o[8];
    o[0] = __float2bfloat16(a.x); o[1] = __float2bfloat16(a.y);
    o[2] = __float2bfloat16(a.z); o[3] = __float2bfloat16(a.w);
    o[4] = __float2bfloat16(b.x); o[5] = __float2bfloat16(b.y);
    o[6] = __float2bfloat16(b.z); o[7] = __float2bfloat16(b.w);
    *(uint4*)(dst + i) = *(const uint4*)o;
}

__global__ void prep_fused(const float* __restrict__ q_in,
                           const float* __restrict__ k_in,
                           const float* __restrict__ rope,
                           const float* __restrict__ bq,
                           const float* __restrict__ bkv,
                           const float* __restrict__ bp,
                           const float* __restrict__ Wq,
                           const float* __restrict__ Wkv,
                           const float* __restrict__ Wp,
                           bf16* __restrict__ qbw, bf16* __restrict__ kbw,
                           bf16* __restrict__ ropec, bf16* __restrict__ bqc,
                           bf16* __restrict__ bkvc, bf16* __restrict__ bpc,
                           bf16* __restrict__ WqT, bf16* __restrict__ WkvT,
                           bf16* __restrict__ WpT) {
    __shared__ bf16 t[32][33];
    int b = blockIdx.x, tid = threadIdx.x;
    if (b < 4096) {
        cast8(q_in, qbw, (b * 256 + tid) * 8);
    } else if (b < 8192) {
        cast8(k_in, kbw, ((b - 4096) * 256 + tid) * 8);
    } else if (b < 8256) {
        cast8(rope, ropec, ((b - 8192) * 256 + tid) * 8);
    } else if (b == 8256) {
        if (tid < 128) cast8(bq, bqc, tid * 8);
        else cast8(bp, bpc, (tid - 128) * 8);
    } else if (b == 8257) {
        cast8(bkv, bkvc, tid * 8);
    } else {
        const int bb = b - 8258;
        const int bx = bb & 127, by = bb >> 7;
        const int tx = tid & 31, ty = tid >> 5;
        const float* in;
        bf16* out;
        int C, bxl;
        if (bx < 32)      { in = Wq;  out = WqT;  C = 1024; bxl = bx; }
        else if (bx < 96) { in = Wkv; out = WkvT; C = 2048; bxl = bx - 32; }
        else              { in = Wp;  out = WpT;  C = 1024; bxl = bx - 96; }
        const int R = 1024;
        int c0 = bxl * 32, r0 = by * 32;
        for (int i = ty; i < 32; i += 8)
            t[i][tx] = __float2bfloat16(in[(size_t)(r0 + i) * C + c0 + tx]);
        __syncthreads();
        for (int i = ty; i < 32; i += 8)
            out[(size_t)(c0 + i) * R + r0 + tx] = t[tx][i];
    }
}

// ---------------------------------------------------------------------------
// Out-projection GEMM: out[M,N] f32 = A[M,K] bf16 @ BT[N,K]^T + bias.
// 2-buffer COUNTED-vmcnt pipeline (unchanged from R13).
// ---------------------------------------------------------------------------
__global__ __launch_bounds__(256) void gemm_out(
    const bf16* __restrict__ A, const bf16* __restrict__ BT,
    const bf16* __restrict__ bias, float* __restrict__ out, int M, int N,
    int K) {
    __shared__ __align__(16) bf16 smA[2][128 * 32];
    __shared__ __align__(16) bf16 smB[2][128 * 32];

    // grid (8,64) = 512 blocks; XCD k gets by in [k*8, k*8+8)
    const int flat = blockIdx.y * 8 + blockIdx.x;
    const int nf = (flat & 7) * 64 + (flat >> 3);
    const int bn0 = (nf & 7) * 128;
    const int bm0 = (nf >> 3) * 128;

    const int tid = threadIdx.x;
    const int lane = tid & 63;
    const int wave = tid >> 6;
    const int lm = lane & 15;
    const int lq = lane >> 4;
    const int wm = (wave >> 1) * 64;
    const int wn = (wave & 1) * 64;

    const int sbase0 = wave * 64;          // wave-uniform slot base, rr=0
    const int sbase1 = 256 + wave * 64;    // rr=1
    const size_t gofs0 = swz_gofs(sbase0 + lane, K);
    const size_t gofs1 = swz_gofs(sbase1 + lane, K);
    const int rc = (lq ^ ((lm >> 1) & 3)) * 8;  // swizzled read-chunk offset

    const f32x4 z4 = {0.f, 0.f, 0.f, 0.f};
    f32x4 acc[4][4];
#pragma unroll
    for (int i = 0; i < 4; ++i)
#pragma unroll
        for (int j = 0; j < 4; ++j) acc[i][j] = z4;

    const bf16* gA0 = A + (size_t)bm0 * K;
    const bf16* gB0 = BT + (size_t)bn0 * K;

    auto stage = [&](int kt, int buf) {
        const bf16* gB = gB0 + kt * 32;
        const bf16* gA = gA0 + kt * 32;
        lds_cp16(gB + gofs0, &smB[buf][0] + (size_t)sbase0 * 8);
        lds_cp16(gB + gofs1, &smB[buf][0] + (size_t)sbase1 * 8);
        lds_cp16(gA + gofs0, &smA[buf][0] + (size_t)sbase0 * 8);
        lds_cp16(gA + gofs1, &smA[buf][0] + (size_t)sbase1 * 8);
    };

    const int nk = K >> 5;
    stage(0, 0);

    for (int kt = 0; kt < nk; ++kt) {
        if (kt + 1 < nk) {
            stage(kt + 1, (kt + 1) & 1);
            asm volatile("s_waitcnt vmcnt(4)" ::: "memory");
        } else {
            asm volatile("s_waitcnt vmcnt(0)" ::: "memory");
        }
        __builtin_amdgcn_s_barrier();

        const int cur = kt & 1;
        s16x8 af[4], bfr[4];
#pragma unroll
        for (int i = 0; i < 4; ++i) {
            af[i] = *(const s16x8*)(&smA[cur][0] + (wm + i * 16 + lm) * 32 + rc);
            bfr[i] =
                *(const s16x8*)(&smB[cur][0] + (wn + i * 16 + lm) * 32 + rc);
        }
#pragma unroll
        for (int i = 0; i < 4; ++i)
#pragma unroll
            for (int j = 0; j < 4; ++j)
                acc[i][j] = MFMA16(af[i], bfr[j], acc[i][j]);

        __builtin_amdgcn_s_barrier();  // readers done before buf overwrite
    }

#pragma unroll
    for (int j = 0; j < 4; ++j) {
        const int n = bn0 + wn + j * 16 + lm;
        const float bv = __bfloat162float(bias[n]);
#pragma unroll
        for (int i = 0; i < 4; ++i) {
#pragma unroll
            for (int r = 0; r < 4; ++r) {
                const int m = bm0 + wm + i * 16 + lq * 4 + r;
                out[(size_t)m * N + n] = acc[i][j][r] + bv;
            }
        }
    }
}

// ---------------------------------------------------------------------------
// Fused Q+KV projection GEMM with RoPE in the epilogue. A is PRE-CAST bf16.
// Q stored PRE-SCALED by SCALE*log2(e). V stored NATURAL transposed.
// 256x128 tile, 4 WAVES (256 thr), per-wave output 64 rows x 128 cols:
// 12 fragment reads (4 A + 8 B) feed 32 MFMAs -> 0.375 KB/MFMA LDS traffic
// (-25% vs 64x64 waves) and 2x MFMA per barrier interval. acc[4][8] = 128
// AGPRs. Staging = 6 lds_cp16/thread -> counted vmcnt(6). 2-buffer pipeline,
// 2D XCD chunking + chunk-XOR swizzle (read key (lm>>1)&3 invariant across
// all i*16/j*16 row offsets since 16-row steps preserve (row>>1)&3).
// ---------------------------------------------------------------------------
__global__ __launch_bounds__(256) void gemm_qkv(
    const bf16* __restrict__ qbw, const bf16* __restrict__ kbw,
    const bf16* __restrict__ WqT, const bf16* __restrict__ WkvT,
    const bf16* __restrict__ bq, const bf16* __restrict__ bkv,
    const bf16* __restrict__ ropec, bf16* __restrict__ qw,
    bf16* __restrict__ kw, bf16* __restrict__ vtw) {
    __shared__ __align__(16) bf16 smA[2][256 * 32];
    __shared__ __align__(16) bf16 smB[2][128 * 32];

    const int K = 1024;
    // grid (24,32)=768; XCD = flat&7 -> (bx half, by quarter) 2D chunk.
    const int flat = blockIdx.y * 24 + blockIdx.x;
    const int xcd = flat & 7;
    const int li = flat >> 3;                 // 0..95 within XCD
    const int bx = (xcd & 1) * 12 + (li % 12);
    const int by = (xcd >> 1) * 8 + (li / 12);

    const bool isq = (bx < 8);
    const bf16* A = isq ? qbw : kbw;
    const bf16* BT = isq ? WqT : WkvT;
    const bf16* bias = isq ? bq : bkv;
    const int bn0 = (isq ? bx : bx - 8) * 128;
    const int bm0 = by * 256;

    const int tid = threadIdx.x;
    const int lane = tid & 63;
    const int wave = tid >> 6;      // 0..3
    const int lm = lane & 15;
    const int lq = lane >> 4;
    const int wm = wave * 64;       // wave's 64-row slice of the 256 rows

    // staging with 256 threads: A = 1024 slots (4 rounds), B = 512 (2 rounds)
    const int sA0 = wave * 64;
    const int sA1 = 256 + wave * 64;
    const int sA2 = 512 + wave * 64;
    const int sA3 = 768 + wave * 64;
    const int sB0 = wave * 64;
    const int sB1 = 256 + wave * 64;
    const size_t gAofs0 = swz_gofs(sA0 + lane, K);
    const size_t gAofs1 = swz_gofs(sA1 + lane, K);
    const size_t gAofs2 = swz_gofs(sA2 + lane, K);
    const size_t gAofs3 = swz_gofs(sA3 + lane, K);
    const size_t gBofs0 = swz_gofs(sB0 + lane, K);
    const size_t gBofs1 = swz_gofs(sB1 + lane, K);
    const int rc = (lq ^ ((lm >> 1) & 3)) * 8;  // swizzled read-chunk offset

    const f32x4 z4 = {0.f, 0.f, 0.f, 0.f};
    f32x4 acc[4][8];
#pragma unroll
    for (int i = 0; i < 4; ++i)
#pragma unroll
        for (int j = 0; j < 8; ++j) acc[i][j] = z4;

    const bf16* gA0 = A + (size_t)bm0 * K;
    const bf16* gB0 = BT + (size_t)bn0 * K;

    auto stage = [&](int kt, int buf) {
        const bf16* gB = gB0 + kt * 32;
        const bf16* gA = gA0 + kt * 32;
        lds_cp16(gB + gBofs0, &smB[buf][0] + (size_t)sB0 * 8);
        lds_cp16(gB + gBofs1, &smB[buf][0] + (size_t)sB1 * 8);
        lds_cp16(gA + gAofs0, &smA[buf][0] + (size_t)sA0 * 8);
        lds_cp16(gA + gAofs1, &smA[buf][0] + (size_t)sA1 * 8);
        lds_cp16(gA + gAofs2, &smA[buf][0] + (size_t)sA2 * 8);
        lds_cp16(gA + gAofs3, &smA[buf][0] + (size_t)sA3 * 8);
    };

    stage(0, 0);

    for (int kt = 0; kt < 32; ++kt) {
        if (kt + 1 < 32) {
            stage(kt + 1, (kt + 1) & 1);
            asm volatile("s_waitcnt vmcnt(6)" ::: "memory");
        } else {
            asm volatile("s_waitcnt vmcnt(0)" ::: "memory");
        }
        __builtin_amdgcn_s_barrier();

        const int cur = kt & 1;
        s16x8 af[4], bfr[8];
#pragma unroll
        for (int i = 0; i < 4; ++i)
            af[i] = *(const s16x8*)(&smA[cur][0] + (wm + i * 16 + lm) * 32 + rc);
#pragma unroll
        for (int j = 0; j < 8; ++j)
            bfr[j] = *(const s16x8*)(&smB[cur][0] + (j * 16 + lm) * 32 + rc);
#pragma unroll
        for (int i = 0; i < 4; ++i)
#pragma unroll
            for (int j = 0; j < 8; ++j)
                acc[i][j] = MFMA16(af[i], bfr[j], acc[i][j]);

        __builtin_amdgcn_s_barrier();  // readers done before buf overwrite
    }

#pragma unroll
    for (int j = 0; j < 8; ++j) {
        const int n = bn0 + j * 16 + lm;
        const float bv = __bfloat162float(bias[n]);
        const bool dorope = isq || n < 1024;   // uniform per (wave,j)
        const int hd0 = n & 63;
        const int p = hd0 >> 1;
#pragma unroll
        for (int i = 0; i < 4; ++i) {
#pragma unroll
            for (int r = 0; r < 4; ++r) {
                const int m = bm0 + wm + i * 16 + lq * 4 + r;
                float v = acc[i][j][r] + bv;
                const int b = m >> 11, l = m & 2047;
                if (dorope) {
                    // partner lane holds the other element of the rope pair
                    float vo = __shfl_xor(v, 1, 64);
                    unsigned sc = ((const unsigned*)ropec)[l * 32 + p];
                    float sn = __uint_as_float(sc << 16);
                    float cs = __uint_as_float(sc & 0xffff0000u);
                    v = (hd0 & 1) ? (vo * sn + v * cs) : (v * cs - vo * sn);
                }
                if (isq) {
                    const int h = n >> 6, hd = n & 63;
                    qw[(((size_t)(b * 16 + h) * 2048) + l) * 64 + hd] =
                        __float2bfloat16(v * SCALE_LOG2E);
                } else if (n >= 1024) {
                    const int n2 = n - 1024;
                    const int h = n2 >> 6, hd = n2 & 63;
                    vtw[(((size_t)(b * 16 + h) * 64) + hd) * 2048 + l] =
                        __float2bfloat16(v);
                } else {
                    const int h = n >> 6, hd = n & 63;
                    kw[(((size_t)(b * 16 + h) * 2048) + l) * 64 + hd] =
                        __float2bfloat16(v);
                }
            }
        }
    }
}

// ---------------------------------------------------------------------------
// Causal attention, swapped-QK^T in-register softmax (no P LDS round-trip).
// Q pre-scaled by SCALE*log2(e) -> softmax is a bare exp2.
// lsum computed ON THE MATRIX PIPE (all-ones B fragment MFMA per tile).
// KVBLK=64 (2 sub-tiles of 32 per interval); pair {i,31-i} equalizes work.
// 2-buffer COUNTED-vmcnt(4) pipeline. V chunk-XOR swizzled; K rows PERMUTED
// at fragment load. Softmax without online max. (unchanged from R13)
// ---------------------------------------------------------------------------
__global__ __launch_bounds__(256) void attn_causal(
    const bf16* __restrict__ Q, const bf16* __restrict__ Kc,
    const bf16* __restrict__ VT, bf16* __restrict__ O) {
    __shared__ __align__(16) bf16 smK[2][4096];  // 2 subtiles [32 r][64 d] swz
    __shared__ __align__(16) bf16 smV[2][4096];  // 2 subtiles [64 hd][32 k] swz

    const int tid = threadIdx.x;
    const int lane = tid & 63;
    const int wave = tid >> 6;
    const int lm = lane & 15;
    const int lq = lane >> 4;

    // grid (16,64)=1024 blocks; XCD k gets bh in [k*8, k*8+8)
    const int flat = blockIdx.y * 16 + blockIdx.x;
    const int nfl = (flat & 7) * 128 + (flat >> 3);
    const int bxs = nfl & 15;
    const int bh = nfl >> 4;

    const int qbA = bxs * 64;          // short tile (few keys)
    const int qbB = (31 - bxs) * 64;   // long tile (many keys)
    const int qA0 = qbA + wave * 16;
    const int qB0 = qbB + wave * 16;

    const bf16* qp = Q + (size_t)bh * 2048 * 64;
    const bf16* kp = Kc + (size_t)bh * 2048 * 64;
    const bf16* vp = VT + (size_t)bh * 64 * 2048;

    // Q fragments (mfma B operand): n=qrow=lane&15, k=lq*8+j
    s16x8 aqA0 = *(const s16x8*)(qp + (size_t)(qA0 + lm) * 64 + lq * 8);
    s16x8 aqA1 = *(const s16x8*)(qp + (size_t)(qA0 + lm) * 64 + 32 + lq * 8);
    s16x8 aqB0 = *(const s16x8*)(qp + (size_t)(qB0 + lm) * 64 + lq * 8);
    s16x8 aqB1 = *(const s16x8*)(qp + (size_t)(qB0 + lm) * 64 + 32 + lq * 8);

    // all-ones bf16 B fragment for the lsum MFMA
    s16x8 ones;
#pragma unroll
    for (int i = 0; i < 8; ++i) ones[i] = (short)0x3F80;

    const f32x4 z4 = {0.f, 0.f, 0.f, 0.f};
    f32x4 oA[4], oB[4], lsA, lsB;
#pragma unroll
    for (int c = 0; c < 4; ++c) { oA[c] = z4; oB[c] = z4; }
    lsA = z4; lsB = z4;

    const int nitA = bxs + 1;        // A consumes chunks [0, nitA)
    const int nit = 33 - nitA;       // B consumes chunks [0, nit); 17..32

    // ---- cooperative staging (per 32-key sub-tile; wave does 1KB each) ----
    const int krow = wave * 8 + (lane >> 3);
    const int kcd = (lane & 7) ^ ((lane >> 3) & 3) ^ ((wave & 1) << 2);
    const int vrow = wave * 16 + (lane >> 2);
    const int vck = (lane & 3) ^ ((lane >> 4) & 3);

    // stage 64-key chunk starting at key kb into buffer buf
    auto stage = [&](int kb, int buf) {
        lds_cp16(kp + (size_t)(kb + krow) * 64 + kcd * 8,
                 &smK[buf][0] + wave * 512);
        lds_cp16(kp + (size_t)(kb + 32 + krow) * 64 + kcd * 8,
                 &smK[buf][0] + 2048 + wave * 512);
        lds_cp16(vp + (size_t)vrow * 2048 + kb + vck * 8,
                 &smV[buf][0] + wave * 512);
        lds_cp16(vp + (size_t)vrow * 2048 + kb + 32 + vck * 8,
                 &smV[buf][0] + 2048 + wave * 512);
    };

    stage(0, 0);

    const int rowgA = qA0 + lm;  // this lane's q-row (tile A)
    const int rowgB = qB0 + lm;  // this lane's q-row (tile B)
    const int lq4 = lq * 4;
    const int lq8 = lq * 8;

    // permuted K fragment row + its swizzle key
    const int pr = 8 * (lm >> 2) + (lm & 3);
    const int fk = (lm & 3) | (((lm >> 2) & 1) << 2);
    const int c0 = ((lq ^ fk) * 8);        // phys chunk offset, d-lo
    const int c1 = (((lq ^ 4) ^ fk) * 8);  // phys chunk offset, d-hi
    const int vc = (lq ^ (lm >> 2)) * 8;   // V phys chunk offset

    for (int it = 0; it < nit; ++it) {
        const int kb = it * 64;
        const int buf = it & 1;
        const bool doA = (it < nitA);

        if (it + 1 < nit) {
            stage(kb + 64, buf ^ 1);
            asm volatile("s_waitcnt vmcnt(4)" ::: "memory");
        } else {
            asm volatile("s_waitcnt vmcnt(0)" ::: "memory");
        }
        __builtin_amdgcn_s_barrier();

#pragma unroll
        for (int s = 0; s < 2; ++s) {
            const int kbs = kb + s * 32;
            const bf16* tK = &smK[buf][0] + s * 2048;
            const bf16* tV = &smV[buf][0] + s * 2048;

            // K fragments (A operand), permuted rows, from swizzled LDS
            s16x8 b00 = *(const s16x8*)(tK + pr * 64 + c0);
            s16x8 b01 = *(const s16x8*)(tK + pr * 64 + c1);
            s16x8 b10 = *(const s16x8*)(tK + (pr + 4) * 64 + c0);
            s16x8 b11 = *(const s16x8*)(tK + (pr + 4) * 64 + c1);
            s16x8 bv[4];
#pragma unroll
            for (int c = 0; c < 4; ++c)
                bv[c] = *(const s16x8*)(tV + (c * 16 + lm) * 32 + vc);

            // swapped QK^T: S^T row lq4+r = key {8lq+r | 8lq+4+r}
            f32x4 sB0 = z4, sB1 = z4, sA0 = z4, sA1 = z4;
            __builtin_amdgcn_s_setprio(1);
            sB0 = MFMA16(b00, aqB0, sB0);
            sB0 = MFMA16(b01, aqB1, sB0);
            sB1 = MFMA16(b10, aqB0, sB1);
            sB1 = MFMA16(b11, aqB1, sB1);
            if (doA) {
                sA0 = MFMA16(b00, aqA0, sA0);
                sA0 = MFMA16(b01, aqA1, sA0);
                sA1 = MFMA16(b10, aqA0, sA1);
                sA1 = MFMA16(b11, aqA1, sA1);
            }
            __builtin_amdgcn_s_setprio(0);

            // exp2 in-register -> PV A-fragment (Q pre-scaled)
            bf16 pbB[8];
            if (kbs + 31 <= qB0) {  // interior: no masking (wave-uniform)
#pragma unroll
                for (int r = 0; r < 4; ++r) {
                    pbB[r] = __float2bfloat16(exp2f(sB0[r]));
                    pbB[4 + r] = __float2bfloat16(exp2f(sB1[r]));
                }
            } else {
#pragma unroll
                for (int r = 0; r < 4; ++r) {
                    float p0 = (kbs + lq8 + r <= rowgB) ? exp2f(sB0[r]) : 0.f;
                    float p1 =
                        (kbs + lq8 + 4 + r <= rowgB) ? exp2f(sB1[r]) : 0.f;
                    pbB[r] = __float2bfloat16(p0);
                    pbB[4 + r] = __float2bfloat16(p1);
                }
            }
            s16x8 paB = *(const s16x8*)pbB;
            __builtin_amdgcn_s_setprio(1);
            oB[0] = MFMA16(paB, bv[0], oB[0]);
            oB[1] = MFMA16(paB, bv[1], oB[1]);
            oB[2] = MFMA16(paB, bv[2], oB[2]);
            oB[3] = MFMA16(paB, bv[3], oB[3]);
            lsB = MFMA16(paB, ones, lsB);
            __builtin_amdgcn_s_setprio(0);

            if (doA) {
                bf16 pbA[8];
                if (kbs + 31 <= qA0) {
#pragma unroll
                    for (int r = 0; r < 4; ++r) {
                        pbA[r] = __float2bfloat16(exp2f(sA0[r]));
                        pbA[4 + r] = __float2bfloat16(exp2f(sA1[r]));
                    }
                } else {
#pragma unroll
                    for (int r = 0; r < 4; ++r) {
                        float p0 =
                            (kbs + lq8 + r <= rowgA) ? exp2f(sA0[r]) : 0.f;
                        float p1 =
                            (kbs + lq8 + 4 + r <= rowgA) ? exp2f(sA1[r]) : 0.f;
                        pbA[r] = __float2bfloat16(p0);
                        pbA[4 + r] = __float2bfloat16(p1);
                    }
                }
                s16x8 paA = *(const s16x8*)pbA;
                __builtin_amdgcn_s_setprio(1);
                oA[0] = MFMA16(paA, bv[0], oA[0]);
                oA[1] = MFMA16(paA, bv[1], oA[1]);
                oA[2] = MFMA16(paA, bv[2], oA[2]);
                oA[3] = MFMA16(paA, bv[3], oA[3]);
                lsA = MFMA16(paA, ones, lsA);
                __builtin_amdgcn_s_setprio(0);
            }
        }

        __builtin_amdgcn_s_barrier();  // readers done before buf overwrite
    }

    // lsA/lsB C-layout == o C-layout: row lq4+r holds that q-row's sum in
    // every column -> divide directly, no cross-lane reduction needed.
    const int b = bh >> 4, h = bh & 15;
#pragma unroll
    for (int c = 0; c < 4; ++c) {
#pragma unroll
        for (int r = 0; r < 4; ++r) {
            const int hd = c * 16 + lm;
            const int lA = qA0 + lq4 + r;
            O[((size_t)(b * 2048 + lA)) * 1024 + h * 64 + hd] =
                __float2bfloat16(oA[c][r] / lsA[r]);
            const int lB = qB0 + lq4 + r;
            O[((size_t)(b * 2048 + lB)) * 1024 + h * 64 + hd] =
                __float2bfloat16(oB[c][r] / lsB[r]);
        }
    }
}

// ---------------------------------------------------------------------------
extern "C" void kernel_launch(void* const* d_in, const int* in_sizes, int n_in,
                              void* d_out, int out_size, void* d_ws,
                              size_t ws_size, hipStream_t stream) {
    // Inputs are f32; output is read by the harness as FLOAT32.
    const float* q_in = (const float*)d_in[0];
    const float* k_in = (const float*)d_in[1];
    // d_in[2] v_in unused by reference; d_in[3] mask: causal by construction
    const float* rope = (const float*)d_in[4];
    const float* Wq = (const float*)d_in[5];
    const float* bq = (const float*)d_in[6];
    const float* Wkv = (const float*)d_in[7];
    const float* bkv = (const float*)d_in[8];
    const float* Wp = (const float*)d_in[9];
    const float* bp = (const float*)d_in[10];
    float* out = (float*)d_out;

    char* ws = (char*)d_ws;
    bf16* bqc = (bf16*)ws;   ws += 2048;
    bf16* bkvc = (bf16*)ws;  ws += 4096;
    bf16* bpc = (bf16*)ws;   ws += 2048;
    bf16* ropec = (bf16*)ws; ws += 262144;
    bf16* WqT = (bf16*)ws;   ws += 2097152;
    bf16* WkvT = (bf16*)ws;  ws += 4194304;
    bf16* WpT = (bf16*)ws;   ws += 2097152;
    bf16* qw = (bf16*)ws;    ws += 16777216;   // [B,H,L,64] (pre-scaled)
    bf16* kw = (bf16*)ws;    ws += 16777216;   // [B,H,L,64]
    bf16* vtw = (bf16*)ws;   ws += 16777216;   // [B,H,64,L]
    bf16* aw = (bf16*)ws;    ws += 16777216;   // [B,L,1024]

    // Scratch aliasing (zero extra workspace):
    //   qbw = aw   (aw is only written later, by attn_causal)
    //   kbw = out  (out is only written later, by gemm_out)
    bf16* qbw = aw;
    bf16* kbw = (bf16*)out;

    dim3 blk(256);

    prep_fused<<<12354, blk, 0, stream>>>(q_in, k_in, rope, bq, bkv, bp, Wq,
                                          Wkv, Wp, qbw, kbw, ropec, bqc, bkvc,
                                          bpc, WqT, WkvT, WpT);

    gemm_qkv<<<dim3(24, 32), blk, 0, stream>>>(qbw, kbw, WqT, WkvT, bqc, bkvc,
                                               ropec, qw, kw, vtw);

    attn_causal<<<dim3(16, 64), blk, 0, stream>>>(qw, kw, vtw, aw);

    gemm_out<<<dim3(8, 64), blk, 0, stream>>>(aw, WpT, bpc, out, 8192, 1024,
                                              1024);
}

// Round 15
// 407.011 us; speedup vs baseline: 1.0362x; 1.0362x over previous
//
#include <hip/hip_runtime.h>
#include <hip/hip_bf16.h>

typedef __hip_bfloat16 bf16;
typedef short s16x8 __attribute__((ext_vector_type(8)));
typedef float f32x4 __attribute__((ext_vector_type(4)));

#define MFMA16(a, b, c) __builtin_amdgcn_mfma_f32_16x16x32_bf16(a, b, c, 0, 0, 0)
#define SCALE 0.125f
// exp(x*SCALE) == exp2(x * SCALE*log2(e)); folded into the Q store.
#define SCALE_LOG2E 0.18033688011112042f

typedef __attribute__((address_space(1))) void gvoid;
typedef __attribute__((address_space(3))) void lvoid;

static __device__ __forceinline__ void lds_cp16(const bf16* g, bf16* l) {
    // async global->LDS, 16B per lane; LDS dest = wave-uniform base + lane*16
    __builtin_amdgcn_global_load_lds((gvoid*)g, (lvoid*)l, 16, 0, 0);
}

// Bank-conflict swizzle for [rows][32] bf16 GEMM tiles (rule #21: both-sides).
// LDS slot s (16B chunks; row = s>>2, chunk = s&3) holds GLOBAL chunk
// (s&3) ^ ((s>>3)&3). Reads XOR the same key: phys chunk = lq ^ ((lm>>1)&3).
static __device__ __forceinline__ size_t swz_gofs(int slot, int K) {
    return (size_t)(slot >> 2) * K + (((slot & 3) ^ ((slot >> 3) & 3)) * 8);
}

// ---------------------------------------------------------------------------
// One fused prep pass: q_in/k_in f32->bf16, rope, biases, and the three
// weight transposes. Blocks: [0,4096) q, [4096,8192) k, [8192,8256) rope,
// 8256 bq/bp, 8257 bkv, [8258, 8258+4096) transpose (128 x 32 tiles).
// ---------------------------------------------------------------------------
static __device__ __forceinline__ void cast8(const float* src, bf16* dst,
                                             int i) {
    float4 a = *(const float4*)(src + i);
    float4 b = *(const float4*)(src + i + 4);
    bf16 o[8];
    o[0] = __float2bfloat16(a.x); o[1] = __float2bfloat16(a.y);
    o[2] = __float2bfloat16(a.z); o[3] = __float2bfloat16(a.w);
    o[4] = __float2bfloat16(b.x); o[5] = __float2bfloat16(b.y);
    o[6] = __float2bfloat16(b.z); o[7] = __float2bfloat16(b.w);
    *(uint4*)(dst + i) = *(const uint4*)o;
}

__global__ void prep_fused(const float* __restrict__ q_in,
                           const float* __restrict__ k_in,
                           const float* __restrict__ rope,
                           const float* __restrict__ bq,
                           const float* __restrict__ bkv,
                           const float* __restrict__ bp,
                           const float* __restrict__ Wq,
                           const float* __restrict__ Wkv,
                           const float* __restrict__ Wp,
                           bf16* __restrict__ qbw, bf16* __restrict__ kbw,
                           bf16* __restrict__ ropec, bf16* __restrict__ bqc,
                           bf16* __restrict__ bkvc, bf16* __restrict__ bpc,
                           bf16* __restrict__ WqT, bf16* __restrict__ WkvT,
                           bf16* __restrict__ WpT) {
    __shared__ bf16 t[32][33];
    int b = blockIdx.x, tid = threadIdx.x;
    if (b < 4096) {
        cast8(q_in, qbw, (b * 256 + tid) * 8);
    } else if (b < 8192) {
        cast8(k_in, kbw, ((b - 4096) * 256 + tid) * 8);
    } else if (b < 8256) {
        cast8(rope, ropec, ((b - 8192) * 256 + tid) * 8);
    } else if (b == 8256) {
        if (tid < 128) cast8(bq, bqc, tid * 8);
        else cast8(bp, bpc, (tid - 128) * 8);
    } else if (b == 8257) {
        cast8(bkv, bkvc, tid * 8);
    } else {
        const int bb = b - 8258;
        const int bx = bb & 127, by = bb >> 7;
        const int tx = tid & 31, ty = tid >> 5;
        const float* in;
        bf16* out;
        int C, bxl;
        if (bx < 32)      { in = Wq;  out = WqT;  C = 1024; bxl = bx; }
        else if (bx < 96) { in = Wkv; out = WkvT; C = 2048; bxl = bx - 32; }
        else              { in = Wp;  out = WpT;  C = 1024; bxl = bx - 96; }
        const int R = 1024;
        int c0 = bxl * 32, r0 = by * 32;
        for (int i = ty; i < 32; i += 8)
            t[i][tx] = __float2bfloat16(in[(size_t)(r0 + i) * C + c0 + tx]);
        __syncthreads();
        for (int i = ty; i < 32; i += 8)
            out[(size_t)(c0 + i) * R + r0 + tx] = t[tx][i];
    }
}

// ---------------------------------------------------------------------------
// Out-projection GEMM: out[M,N] f32 = A[M,K] bf16 @ BT[N,K]^T + bias.
// 2-buffer COUNTED-vmcnt pipeline + setprio around the MFMA cluster (T5:
// the counted-vmcnt pipeline de-lockstepped the waves -> role-split exists).
// ---------------------------------------------------------------------------
__global__ __launch_bounds__(256) void gemm_out(
    const bf16* __restrict__ A, const bf16* __restrict__ BT,
    const bf16* __restrict__ bias, float* __restrict__ out, int M, int N,
    int K) {
    __shared__ __align__(16) bf16 smA[2][128 * 32];
    __shared__ __align__(16) bf16 smB[2][128 * 32];

    // grid (8,64) = 512 blocks; XCD k gets by in [k*8, k*8+8)
    const int flat = blockIdx.y * 8 + blockIdx.x;
    const int nf = (flat & 7) * 64 + (flat >> 3);
    const int bn0 = (nf & 7) * 128;
    const int bm0 = (nf >> 3) * 128;

    const int tid = threadIdx.x;
    const int lane = tid & 63;
    const int wave = tid >> 6;
    const int lm = lane & 15;
    const int lq = lane >> 4;
    const int wm = (wave >> 1) * 64;
    const int wn = (wave & 1) * 64;

    const int sbase0 = wave * 64;          // wave-uniform slot base, rr=0
    const int sbase1 = 256 + wave * 64;    // rr=1
    const size_t gofs0 = swz_gofs(sbase0 + lane, K);
    const size_t gofs1 = swz_gofs(sbase1 + lane, K);
    const int rc = (lq ^ ((lm >> 1) & 3)) * 8;  // swizzled read-chunk offset

    const f32x4 z4 = {0.f, 0.f, 0.f, 0.f};
    f32x4 acc[4][4];
#pragma unroll
    for (int i = 0; i < 4; ++i)
#pragma unroll
        for (int j = 0; j < 4; ++j) acc[i][j] = z4;

    const bf16* gA0 = A + (size_t)bm0 * K;
    const bf16* gB0 = BT + (size_t)bn0 * K;

    auto stage = [&](int kt, int buf) {
        const bf16* gB = gB0 + kt * 32;
        const bf16* gA = gA0 + kt * 32;
        lds_cp16(gB + gofs0, &smB[buf][0] + (size_t)sbase0 * 8);
        lds_cp16(gB + gofs1, &smB[buf][0] + (size_t)sbase1 * 8);
        lds_cp16(gA + gofs0, &smA[buf][0] + (size_t)sbase0 * 8);
        lds_cp16(gA + gofs1, &smA[buf][0] + (size_t)sbase1 * 8);
    };

    const int nk = K >> 5;
    stage(0, 0);

    for (int kt = 0; kt < nk; ++kt) {
        if (kt + 1 < nk) {
            stage(kt + 1, (kt + 1) & 1);
            asm volatile("s_waitcnt vmcnt(4)" ::: "memory");
        } else {
            asm volatile("s_waitcnt vmcnt(0)" ::: "memory");
        }
        __builtin_amdgcn_s_barrier();

        const int cur = kt & 1;
        s16x8 af[4], bfr[4];
#pragma unroll
        for (int i = 0; i < 4; ++i) {
            af[i] = *(const s16x8*)(&smA[cur][0] + (wm + i * 16 + lm) * 32 + rc);
            bfr[i] =
                *(const s16x8*)(&smB[cur][0] + (wn + i * 16 + lm) * 32 + rc);
        }
        __builtin_amdgcn_s_setprio(1);
#pragma unroll
        for (int i = 0; i < 4; ++i)
#pragma unroll
            for (int j = 0; j < 4; ++j)
                acc[i][j] = MFMA16(af[i], bfr[j], acc[i][j]);
        __builtin_amdgcn_s_setprio(0);

        __builtin_amdgcn_s_barrier();  // readers done before buf overwrite
    }

#pragma unroll
    for (int j = 0; j < 4; ++j) {
        const int n = bn0 + wn + j * 16 + lm;
        const float bv = __bfloat162float(bias[n]);
#pragma unroll
        for (int i = 0; i < 4; ++i) {
#pragma unroll
            for (int r = 0; r < 4; ++r) {
                const int m = bm0 + wm + i * 16 + lq * 4 + r;
                out[(size_t)m * N + n] = acc[i][j][r] + bv;
            }
        }
    }
}

// ---------------------------------------------------------------------------
// Fused Q+KV projection GEMM with RoPE in the epilogue. A is PRE-CAST bf16.
// Q stored PRE-SCALED by SCALE*log2(e). V stored NATURAL transposed.
// R13 configuration RESTORED (R14's 4-wave retile cut occupancy 31->17% and
// regressed): 256x128 tile, 512 threads = 8 waves (4M x 2N), per-wave 64x64,
// 48KB LDS -> 3 blocks/CU = 24 waves/CU. 2-buffer COUNTED-vmcnt(3) pipeline.
// 2D XCD chunking + chunk-XOR swizzle. + setprio around MFMA cluster (T5).
// ---------------------------------------------------------------------------
__global__ __launch_bounds__(512) void gemm_qkv(
    const bf16* __restrict__ qbw, const bf16* __restrict__ kbw,
    const bf16* __restrict__ WqT, const bf16* __restrict__ WkvT,
    const bf16* __restrict__ bq, const bf16* __restrict__ bkv,
    const bf16* __restrict__ ropec, bf16* __restrict__ qw,
    bf16* __restrict__ kw, bf16* __restrict__ vtw) {
    __shared__ __align__(16) bf16 smA[2][256 * 32];
    __shared__ __align__(16) bf16 smB[2][128 * 32];

    const int K = 1024;
    // grid (24,32)=768; XCD = flat&7 -> (bx half, by quarter) 2D chunk.
    const int flat = blockIdx.y * 24 + blockIdx.x;
    const int xcd = flat & 7;
    const int li = flat >> 3;                 // 0..95 within XCD
    const int bx = (xcd & 1) * 12 + (li % 12);
    const int by = (xcd >> 1) * 8 + (li / 12);

    const bool isq = (bx < 8);
    const bf16* A = isq ? qbw : kbw;
    const bf16* BT = isq ? WqT : WkvT;
    const bf16* bias = isq ? bq : bkv;
    const int bn0 = (isq ? bx : bx - 8) * 128;
    const int bm0 = by * 256;

    const int tid = threadIdx.x;
    const int lane = tid & 63;
    const int wave = tid >> 6;      // 0..7
    const int lm = lane & 15;
    const int lq = lane >> 4;
    const int wm = (wave >> 1) * 64;   // 4 M-groups cover 256 rows
    const int wn = (wave & 1) * 64;    // 2 N-groups cover 128 cols

    // staging: A = 1024 slots (256 rows x 4 chunks), 2 per thread;
    //          B = 512 slots (128 rows x 4 chunks), 1 per thread.
    const int sA0 = wave * 64;
    const int sA1 = 512 + wave * 64;
    const int sB = wave * 64;
    const size_t gAofs0 = swz_gofs(sA0 + lane, K);
    const size_t gAofs1 = swz_gofs(sA1 + lane, K);
    const size_t gBofs = swz_gofs(sB + lane, K);
    const int rc = (lq ^ ((lm >> 1) & 3)) * 8;  // swizzled read-chunk offset

    const f32x4 z4 = {0.f, 0.f, 0.f, 0.f};
    f32x4 acc[4][4];
#pragma unroll
    for (int i = 0; i < 4; ++i)
#pragma unroll
        for (int j = 0; j < 4; ++j) acc[i][j] = z4;

    const bf16* gA0 = A + (size_t)bm0 * K;
    const bf16* gB0 = BT + (size_t)bn0 * K;

    auto stage = [&](int kt, int buf) {
        const bf16* gB = gB0 + kt * 32;
        const bf16* gA = gA0 + kt * 32;
        lds_cp16(gB + gBofs, &smB[buf][0] + (size_t)sB * 8);
        lds_cp16(gA + gAofs0, &smA[buf][0] + (size_t)sA0 * 8);
        lds_cp16(gA + gAofs1, &smA[buf][0] + (size_t)sA1 * 8);
    };

    stage(0, 0);

    for (int kt = 0; kt < 32; ++kt) {
        if (kt + 1 < 32) {
            stage(kt + 1, (kt + 1) & 1);
            asm volatile("s_waitcnt vmcnt(3)" ::: "memory");
        } else {
            asm volatile("s_waitcnt vmcnt(0)" ::: "memory");
        }
        __builtin_amdgcn_s_barrier();

        const int cur = kt & 1;
        s16x8 af[4], bfr[4];
#pragma unroll
        for (int i = 0; i < 4; ++i) {
            af[i] = *(const s16x8*)(&smA[cur][0] + (wm + i * 16 + lm) * 32 + rc);
            bfr[i] =
                *(const s16x8*)(&smB[cur][0] + (wn + i * 16 + lm) * 32 + rc);
        }
        __builtin_amdgcn_s_setprio(1);
#pragma unroll
        for (int i = 0; i < 4; ++i)
#pragma unroll
            for (int j = 0; j < 4; ++j)
                acc[i][j] = MFMA16(af[i], bfr[j], acc[i][j]);
        __builtin_amdgcn_s_setprio(0);

        __builtin_amdgcn_s_barrier();  // readers done before buf overwrite
    }

#pragma unroll
    for (int j = 0; j < 4; ++j) {
        const int n = bn0 + wn + j * 16 + lm;
        const float bv = __bfloat162float(bias[n]);
        const bool dorope = isq || n < 1024;   // uniform per (wave,j)
        const int hd0 = n & 63;
        const int p = hd0 >> 1;
#pragma unroll
        for (int i = 0; i < 4; ++i) {
#pragma unroll
            for (int r = 0; r < 4; ++r) {
                const int m = bm0 + wm + i * 16 + lq * 4 + r;
                float v = acc[i][j][r] + bv;
                const int b = m >> 11, l = m & 2047;
                if (dorope) {
                    // partner lane holds the other element of the rope pair
                    float vo = __shfl_xor(v, 1, 64);
                    unsigned sc = ((const unsigned*)ropec)[l * 32 + p];
                    float sn = __uint_as_float(sc << 16);
                    float cs = __uint_as_float(sc & 0xffff0000u);
                    v = (hd0 & 1) ? (vo * sn + v * cs) : (v * cs - vo * sn);
                }
                if (isq) {
                    const int h = n >> 6, hd = n & 63;
                    qw[(((size_t)(b * 16 + h) * 2048) + l) * 64 + hd] =
                        __float2bfloat16(v * SCALE_LOG2E);
                } else if (n >= 1024) {
                    const int n2 = n - 1024;
                    const int h = n2 >> 6, hd = n2 & 63;
                    vtw[(((size_t)(b * 16 + h) * 64) + hd) * 2048 + l] =
                        __float2bfloat16(v);
                } else {
                    const int h = n >> 6, hd = n & 63;
                    kw[(((size_t)(b * 16 + h) * 2048) + l) * 64 + hd] =
                        __float2bfloat16(v);
                }
            }
        }
    }
}

// ---------------------------------------------------------------------------
// Causal attention, swapped-QK^T in-register softmax (no P LDS round-trip).
// Q pre-scaled by SCALE*log2(e) -> softmax is a bare exp2.
// lsum computed ON THE MATRIX PIPE (all-ones B fragment MFMA per tile).
// KVBLK=64 (2 sub-tiles of 32 per interval); pair {i,31-i} equalizes work.
// 2-buffer COUNTED-vmcnt(4) pipeline. V chunk-XOR swizzled; K rows PERMUTED
// at fragment load. Softmax without online max. (unchanged from R13)
// ---------------------------------------------------------------------------
__global__ __launch_bounds__(256) void attn_causal(
    const bf16* __restrict__ Q, const bf16* __restrict__ Kc,
    const bf16* __restrict__ VT, bf16* __restrict__ O) {
    __shared__ __align__(16) bf16 smK[2][4096];  // 2 subtiles [32 r][64 d] swz
    __shared__ __align__(16) bf16 smV[2][4096];  // 2 subtiles [64 hd][32 k] swz

    const int tid = threadIdx.x;
    const int lane = tid & 63;
    const int wave = tid >> 6;
    const int lm = lane & 15;
    const int lq = lane >> 4;

    // grid (16,64)=1024 blocks; XCD k gets bh in [k*8, k*8+8)
    const int flat = blockIdx.y * 16 + blockIdx.x;
    const int nfl = (flat & 7) * 128 + (flat >> 3);
    const int bxs = nfl & 15;
    const int bh = nfl >> 4;

    const int qbA = bxs * 64;          // short tile (few keys)
    const int qbB = (31 - bxs) * 64;   // long tile (many keys)
    const int qA0 = qbA + wave * 16;
    const int qB0 = qbB + wave * 16;

    const bf16* qp = Q + (size_t)bh * 2048 * 64;
    const bf16* kp = Kc + (size_t)bh * 2048 * 64;
    const bf16* vp = VT + (size_t)bh * 64 * 2048;

    // Q fragments (mfma B operand): n=qrow=lane&15, k=lq*8+j
    s16x8 aqA0 = *(const s16x8*)(qp + (size_t)(qA0 + lm) * 64 + lq * 8);
    s16x8 aqA1 = *(const s16x8*)(qp + (size_t)(qA0 + lm) * 64 + 32 + lq * 8);
    s16x8 aqB0 = *(const s16x8*)(qp + (size_t)(qB0 + lm) * 64 + lq * 8);
    s16x8 aqB1 = *(const s16x8*)(qp + (size_t)(qB0 + lm) * 64 + 32 + lq * 8);

    // all-ones bf16 B fragment for the lsum MFMA
    s16x8 ones;
#pragma unroll
    for (int i = 0; i < 8; ++i) ones[i] = (short)0x3F80;

    const f32x4 z4 = {0.f, 0.f, 0.f, 0.f};
    f32x4 oA[4], oB[4], lsA, lsB;
#pragma unroll
    for (int c = 0; c < 4; ++c) { oA[c] = z4; oB[c] = z4; }
    lsA = z4; lsB = z4;

    const int nitA = bxs + 1;        // A consumes chunks [0, nitA)
    const int nit = 33 - nitA;       // B consumes chunks [0, nit); 17..32

    // ---- cooperative staging (per 32-key sub-tile; wave does 1KB each) ----
    const int krow = wave * 8 + (lane >> 3);
    const int kcd = (lane & 7) ^ ((lane >> 3) & 3) ^ ((wave & 1) << 2);
    const int vrow = wave * 16 + (lane >> 2);
    const int vck = (lane & 3) ^ ((lane >> 4) & 3);

    // stage 64-key chunk starting at key kb into buffer buf
    auto stage = [&](int kb, int buf) {
        lds_cp16(kp + (size_t)(kb + krow) * 64 + kcd * 8,
                 &smK[buf][0] + wave * 512);
        lds_cp16(kp + (size_t)(kb + 32 + krow) * 64 + kcd * 8,
                 &smK[buf][0] + 2048 + wave * 512);
        lds_cp16(vp + (size_t)vrow * 2048 + kb + vck * 8,
                 &smV[buf][0] + wave * 512);
        lds_cp16(vp + (size_t)vrow * 2048 + kb + 32 + vck * 8,
                 &smV[buf][0] + 2048 + wave * 512);
    };

    stage(0, 0);

    const int rowgA = qA0 + lm;  // this lane's q-row (tile A)
    const int rowgB = qB0 + lm;  // this lane's q-row (tile B)
    const int lq4 = lq * 4;
    const int lq8 = lq * 8;

    // permuted K fragment row + its swizzle key
    const int pr = 8 * (lm >> 2) + (lm & 3);
    const int fk = (lm & 3) | (((lm >> 2) & 1) << 2);
    const int c0 = ((lq ^ fk) * 8);        // phys chunk offset, d-lo
    const int c1 = (((lq ^ 4) ^ fk) * 8);  // phys chunk offset, d-hi
    const int vc = (lq ^ (lm >> 2)) * 8;   // V phys chunk offset

    for (int it = 0; it < nit; ++it) {
        const int kb = it * 64;
        const int buf = it & 1;
        const bool doA = (it < nitA);

        if (it + 1 < nit) {
            stage(kb + 64, buf ^ 1);
            asm volatile("s_waitcnt vmcnt(4)" ::: "memory");
        } else {
            asm volatile("s_waitcnt vmcnt(0)" ::: "memory");
        }
        __builtin_amdgcn_s_barrier();

#pragma unroll
        for (int s = 0; s < 2; ++s) {
            const int kbs = kb + s * 32;
            const bf16* tK = &smK[buf][0] + s * 2048;
            const bf16* tV = &smV[buf][0] + s * 2048;

            // K fragments (A operand), permuted rows, from swizzled LDS
            s16x8 b00 = *(const s16x8*)(tK + pr * 64 + c0);
            s16x8 b01 = *(const s16x8*)(tK + pr * 64 + c1);
            s16x8 b10 = *(const s16x8*)(tK + (pr + 4) * 64 + c0);
            s16x8 b11 = *(const s16x8*)(tK + (pr + 4) * 64 + c1);
            s16x8 bv[4];
#pragma unroll
            for (int c = 0; c < 4; ++c)
                bv[c] = *(const s16x8*)(tV + (c * 16 + lm) * 32 + vc);

            // swapped QK^T: S^T row lq4+r = key {8lq+r | 8lq+4+r}
            f32x4 sB0 = z4, sB1 = z4, sA0 = z4, sA1 = z4;
            __builtin_amdgcn_s_setprio(1);
            sB0 = MFMA16(b00, aqB0, sB0);
            sB0 = MFMA16(b01, aqB1, sB0);
            sB1 = MFMA16(b10, aqB0, sB1);
            sB1 = MFMA16(b11, aqB1, sB1);
            if (doA) {
                sA0 = MFMA16(b00, aqA0, sA0);
                sA0 = MFMA16(b01, aqA1, sA0);
                sA1 = MFMA16(b10, aqA0, sA1);
                sA1 = MFMA16(b11, aqA1, sA1);
            }
            __builtin_amdgcn_s_setprio(0);

            // exp2 in-register -> PV A-fragment (Q pre-scaled)
            bf16 pbB[8];
            if (kbs + 31 <= qB0) {  // interior: no masking (wave-uniform)
#pragma unroll
                for (int r = 0; r < 4; ++r) {
                    pbB[r] = __float2bfloat16(exp2f(sB0[r]));
                    pbB[4 + r] = __float2bfloat16(exp2f(sB1[r]));
                }
            } else {
#pragma unroll
                for (int r = 0; r < 4; ++r) {
                    float p0 = (kbs + lq8 + r <= rowgB) ? exp2f(sB0[r]) : 0.f;
                    float p1 =
                        (kbs + lq8 + 4 + r <= rowgB) ? exp2f(sB1[r]) : 0.f;
                    pbB[r] = __float2bfloat16(p0);
                    pbB[4 + r] = __float2bfloat16(p1);
                }
            }
            s16x8 paB = *(const s16x8*)pbB;
            __builtin_amdgcn_s_setprio(1);
            oB[0] = MFMA16(paB, bv[0], oB[0]);
            oB[1] = MFMA16(paB, bv[1], oB[1]);
            oB[2] = MFMA16(paB, bv[2], oB[2]);
            oB[3] = MFMA16(paB, bv[3], oB[3]);
            lsB = MFMA16(paB, ones, lsB);
            __builtin_amdgcn_s_setprio(0);

            if (doA) {
                bf16 pbA[8];
                if (kbs + 31 <= qA0) {
#pragma unroll
                    for (int r = 0; r < 4; ++r) {
                        pbA[r] = __float2bfloat16(exp2f(sA0[r]));
                        pbA[4 + r] = __float2bfloat16(exp2f(sA1[r]));
                    }
                } else {
#pragma unroll
                    for (int r = 0; r < 4; ++r) {
                        float p0 =
                            (kbs + lq8 + r <= rowgA) ? exp2f(sA0[r]) : 0.f;
                        float p1 =
                            (kbs + lq8 + 4 + r <= rowgA) ? exp2f(sA1[r]) : 0.f;
                        pbA[r] = __float2bfloat16(p0);
                        pbA[4 + r] = __float2bfloat16(p1);
                    }
                }
                s16x8 paA = *(const s16x8*)pbA;
                __builtin_amdgcn_s_setprio(1);
                oA[0] = MFMA16(paA, bv[0], oA[0]);
                oA[1] = MFMA16(paA, bv[1], oA[1]);
                oA[2] = MFMA16(paA, bv[2], oA[2]);
                oA[3] = MFMA16(paA, bv[3], oA[3]);
                lsA = MFMA16(paA, ones, lsA);
                __builtin_amdgcn_s_setprio(0);
            }
        }

        __builtin_amdgcn_s_barrier();  // readers done before buf overwrite
    }

    // lsA/lsB C-layout == o C-layout: row lq4+r holds that q-row's sum in
    // every column -> divide directly, no cross-lane reduction needed.
    const int b = bh >> 4, h = bh & 15;
#pragma unroll
    for (int c = 0; c < 4; ++c) {
#pragma unroll
        for (int r = 0; r < 4; ++r) {
            const int hd = c * 16 + lm;
            const int lA = qA0 + lq4 + r;
            O[((size_t)(b * 2048 + lA)) * 1024 + h * 64 + hd] =
                __float2bfloat16(oA[c][r] / lsA[r]);
            const int lB = qB0 + lq4 + r;
            O[((size_t)(b * 2048 + lB)) * 1024 + h * 64 + hd] =
                __float2bfloat16(oB[c][r] / lsB[r]);
        }
    }
}

// ---------------------------------------------------------------------------
extern "C" void kernel_launch(void* const* d_in, const int* in_sizes, int n_in,
                              void* d_out, int out_size, void* d_ws,
                              size_t ws_size, hipStream_t stream) {
    // Inputs are f32; output is read by the harness as FLOAT32.
    const float* q_in = (const float*)d_in[0];
    const float* k_in = (const float*)d_in[1];
    // d_in[2] v_in unused by reference; d_in[3] mask: causal by construction
    const float* rope = (const float*)d_in[4];
    const float* Wq = (const float*)d_in[5];
    const float* bq = (const float*)d_in[6];
    const float* Wkv = (const float*)d_in[7];
    const float* bkv = (const float*)d_in[8];
    const float* Wp = (const float*)d_in[9];
    const float* bp = (const float*)d_in[10];
    float* out = (float*)d_out;

    char* ws = (char*)d_ws;
    bf16* bqc = (bf16*)ws;   ws += 2048;
    bf16* bkvc = (bf16*)ws;  ws += 4096;
    bf16* bpc = (bf16*)ws;   ws += 2048;
    bf16* ropec = (bf16*)ws; ws += 262144;
    bf16* WqT = (bf16*)ws;   ws += 2097152;
    bf16* WkvT = (bf16*)ws;  ws += 4194304;
    bf16* WpT = (bf16*)ws;   ws += 2097152;
    bf16* qw = (bf16*)ws;    ws += 16777216;   // [B,H,L,64] (pre-scaled)
    bf16* kw = (bf16*)ws;    ws += 16777216;   // [B,H,L,64]
    bf16* vtw = (bf16*)ws;   ws += 16777216;   // [B,H,64,L]
    bf16* aw = (bf16*)ws;    ws += 16777216;   // [B,L,1024]

    // Scratch aliasing (zero extra workspace):
    //   qbw = aw   (aw is only written later, by attn_causal)
    //   kbw = out  (out is only written later, by gemm_out)
    bf16* qbw = aw;
    bf16* kbw = (bf16*)out;

    dim3 blk(256);

    prep_fused<<<12354, blk, 0, stream>>>(q_in, k_in, rope, bq, bkv, bp, Wq,
                                          Wkv, Wp, qbw, kbw, ropec, bqc, bkvc,
                                          bpc, WqT, WkvT, WpT);

    gemm_qkv<<<dim3(24, 32), dim3(512), 0, stream>>>(qbw, kbw, WqT, WkvT, bqc,
                                                     bkvc, ropec, qw, kw, vtw);

    attn_causal<<<dim3(16, 64), blk, 0, stream>>>(qw, kw, vtw, aw);

    gemm_out<<<dim3(8, 64), blk, 0, stream>>>(aw, WpT, bpc, out, 8192, 1024,
                                              1024);
}

// Round 16
// 391.669 us; speedup vs baseline: 1.0767x; 1.0392x over previous
//
#include <hip/hip_runtime.h>
#include <hip/hip_bf16.h>

typedef __hip_bfloat16 bf16;
typedef short s16x8 __attribute__((ext_vector_type(8)));
typedef float f32x4 __attribute__((ext_vector_type(4)));

#define MFMA16(a, b, c) __builtin_amdgcn_mfma_f32_16x16x32_bf16(a, b, c, 0, 0, 0)
#define SCALE 0.125f
// exp(x*SCALE) == exp2(x * SCALE*log2(e)); folded into the Q store.
#define SCALE_LOG2E 0.18033688011112042f

typedef __attribute__((address_space(1))) void gvoid;
typedef __attribute__((address_space(3))) void lvoid;

static __device__ __forceinline__ void lds_cp16(const bf16* g, bf16* l) {
    // async global->LDS, 16B per lane; LDS dest = wave-uniform base + lane*16
    __builtin_amdgcn_global_load_lds((gvoid*)g, (lvoid*)l, 16, 0, 0);
}

// Bank-conflict swizzle for [rows][32] bf16 GEMM tiles (rule #21: both-sides).
// LDS slot s (16B chunks; row = s>>2, chunk = s&3) holds GLOBAL chunk
// (s&3) ^ ((s>>3)&3). Reads XOR the same key: phys chunk = lq ^ ((lm>>1)&3).
static __device__ __forceinline__ size_t swz_gofs(int slot, int K) {
    return (size_t)(slot >> 2) * K + (((slot & 3) ^ ((slot >> 3) & 3)) * 8);
}

// ---------------------------------------------------------------------------
// One fused prep pass: q_in/k_in f32->bf16, rope, biases, and the three
// weight transposes. Blocks: [0,4096) q, [4096,8192) k, [8192,8256) rope,
// 8256 bq/bp, 8257 bkv, [8258, 8258+4096) transpose (128 x 32 tiles).
// ---------------------------------------------------------------------------
static __device__ __forceinline__ void cast8(const float* src, bf16* dst,
                                             int i) {
    float4 a = *(const float4*)(src + i);
    float4 b = *(const float4*)(src + i + 4);
    bf16 o[8];
    o[0] = __float2bfloat16(a.x); o[1] = __float2bfloat16(a.y);
    o[2] = __float2bfloat16(a.z); o[3] = __float2bfloat16(a.w);
    o[4] = __float2bfloat16(b.x); o[5] = __float2bfloat16(b.y);
    o[6] = __float2bfloat16(b.z); o[7] = __float2bfloat16(b.w);
    *(uint4*)(dst + i) = *(const uint4*)o;
}

__global__ void prep_fused(const float* __restrict__ q_in,
                           const float* __restrict__ k_in,
                           const float* __restrict__ rope,
                           const float* __restrict__ bq,
                           const float* __restrict__ bkv,
                           const float* __restrict__ bp,
                           const float* __restrict__ Wq,
                           const float* __restrict__ Wkv,
                           const float* __restrict__ Wp,
                           bf16* __restrict__ qbw, bf16* __restrict__ kbw,
                           bf16* __restrict__ ropec, bf16* __restrict__ bqc,
                           bf16* __restrict__ bkvc, bf16* __restrict__ bpc,
                           bf16* __restrict__ WqT, bf16* __restrict__ WkvT,
                           bf16* __restrict__ WpT) {
    __shared__ bf16 t[32][33];
    int b = blockIdx.x, tid = threadIdx.x;
    if (b < 4096) {
        cast8(q_in, qbw, (b * 256 + tid) * 8);
    } else if (b < 8192) {
        cast8(k_in, kbw, ((b - 4096) * 256 + tid) * 8);
    } else if (b < 8256) {
        cast8(rope, ropec, ((b - 8192) * 256 + tid) * 8);
    } else if (b == 8256) {
        if (tid < 128) cast8(bq, bqc, tid * 8);
        else cast8(bp, bpc, (tid - 128) * 8);
    } else if (b == 8257) {
        cast8(bkv, bkvc, tid * 8);
    } else {
        const int bb = b - 8258;
        const int bx = bb & 127, by = bb >> 7;
        const int tx = tid & 31, ty = tid >> 5;
        const float* in;
        bf16* out;
        int C, bxl;
        if (bx < 32)      { in = Wq;  out = WqT;  C = 1024; bxl = bx; }
        else if (bx < 96) { in = Wkv; out = WkvT; C = 2048; bxl = bx - 32; }
        else              { in = Wp;  out = WpT;  C = 1024; bxl = bx - 96; }
        const int R = 1024;
        int c0 = bxl * 32, r0 = by * 32;
        for (int i = ty; i < 32; i += 8)
            t[i][tx] = __float2bfloat16(in[(size_t)(r0 + i) * C + c0 + tx]);
        __syncthreads();
        for (int i = ty; i < 32; i += 8)
            out[(size_t)(c0 + i) * R + r0 + tx] = t[tx][i];
    }
}

// ---------------------------------------------------------------------------
// Out-projection GEMM: out[M,N] f32 = A[M,K] bf16 @ BT[N,K]^T + bias.
// 2-buffer COUNTED-vmcnt pipeline (R13 exact; NO setprio -- R15 showed
// setprio between ds_reads and MFMAs fences the compiler's interleave and
// cost ~28us on the qkv GEMM).
// ---------------------------------------------------------------------------
__global__ __launch_bounds__(256) void gemm_out(
    const bf16* __restrict__ A, const bf16* __restrict__ BT,
    const bf16* __restrict__ bias, float* __restrict__ out, int M, int N,
    int K) {
    __shared__ __align__(16) bf16 smA[2][128 * 32];
    __shared__ __align__(16) bf16 smB[2][128 * 32];

    // grid (8,64) = 512 blocks; XCD k gets by in [k*8, k*8+8)
    const int flat = blockIdx.y * 8 + blockIdx.x;
    const int nf = (flat & 7) * 64 + (flat >> 3);
    const int bn0 = (nf & 7) * 128;
    const int bm0 = (nf >> 3) * 128;

    const int tid = threadIdx.x;
    const int lane = tid & 63;
    const int wave = tid >> 6;
    const int lm = lane & 15;
    const int lq = lane >> 4;
    const int wm = (wave >> 1) * 64;
    const int wn = (wave & 1) * 64;

    const int sbase0 = wave * 64;          // wave-uniform slot base, rr=0
    const int sbase1 = 256 + wave * 64;    // rr=1
    const size_t gofs0 = swz_gofs(sbase0 + lane, K);
    const size_t gofs1 = swz_gofs(sbase1 + lane, K);
    const int rc = (lq ^ ((lm >> 1) & 3)) * 8;  // swizzled read-chunk offset

    const f32x4 z4 = {0.f, 0.f, 0.f, 0.f};
    f32x4 acc[4][4];
#pragma unroll
    for (int i = 0; i < 4; ++i)
#pragma unroll
        for (int j = 0; j < 4; ++j) acc[i][j] = z4;

    const bf16* gA0 = A + (size_t)bm0 * K;
    const bf16* gB0 = BT + (size_t)bn0 * K;

    auto stage = [&](int kt, int buf) {
        const bf16* gB = gB0 + kt * 32;
        const bf16* gA = gA0 + kt * 32;
        lds_cp16(gB + gofs0, &smB[buf][0] + (size_t)sbase0 * 8);
        lds_cp16(gB + gofs1, &smB[buf][0] + (size_t)sbase1 * 8);
        lds_cp16(gA + gofs0, &smA[buf][0] + (size_t)sbase0 * 8);
        lds_cp16(gA + gofs1, &smA[buf][0] + (size_t)sbase1 * 8);
    };

    const int nk = K >> 5;
    stage(0, 0);

    for (int kt = 0; kt < nk; ++kt) {
        if (kt + 1 < nk) {
            stage(kt + 1, (kt + 1) & 1);
            asm volatile("s_waitcnt vmcnt(4)" ::: "memory");
        } else {
            asm volatile("s_waitcnt vmcnt(0)" ::: "memory");
        }
        __builtin_amdgcn_s_barrier();

        const int cur = kt & 1;
        s16x8 af[4], bfr[4];
#pragma unroll
        for (int i = 0; i < 4; ++i) {
            af[i] = *(const s16x8*)(&smA[cur][0] + (wm + i * 16 + lm) * 32 + rc);
            bfr[i] =
                *(const s16x8*)(&smB[cur][0] + (wn + i * 16 + lm) * 32 + rc);
        }
#pragma unroll
        for (int i = 0; i < 4; ++i)
#pragma unroll
            for (int j = 0; j < 4; ++j)
                acc[i][j] = MFMA16(af[i], bfr[j], acc[i][j]);

        __builtin_amdgcn_s_barrier();  // readers done before buf overwrite
    }

#pragma unroll
    for (int j = 0; j < 4; ++j) {
        const int n = bn0 + wn + j * 16 + lm;
        const float bv = __bfloat162float(bias[n]);
#pragma unroll
        for (int i = 0; i < 4; ++i) {
#pragma unroll
            for (int r = 0; r < 4; ++r) {
                const int m = bm0 + wm + i * 16 + lq * 4 + r;
                out[(size_t)m * N + n] = acc[i][j][r] + bv;
            }
        }
    }
}

// ---------------------------------------------------------------------------
// Fused Q+KV projection GEMM with RoPE in the epilogue. A is PRE-CAST bf16.
// Q stored PRE-SCALED by SCALE*log2(e). V stored NATURAL transposed.
// R13 EXACT configuration (best measured: 106.5us): 256x128 tile, 512
// threads = 8 waves (4M x 2N), per-wave 64x64, 48KB LDS -> 3 blocks/CU.
// 2-buffer COUNTED-vmcnt(3) pipeline, 2D XCD chunking, chunk-XOR swizzle.
// NO setprio (R15: it fenced the read->MFMA interleave, -28us).
// ---------------------------------------------------------------------------
__global__ __launch_bounds__(512) void gemm_qkv(
    const bf16* __restrict__ qbw, const bf16* __restrict__ kbw,
    const bf16* __restrict__ WqT, const bf16* __restrict__ WkvT,
    const bf16* __restrict__ bq, const bf16* __restrict__ bkv,
    const bf16* __restrict__ ropec, bf16* __restrict__ qw,
    bf16* __restrict__ kw, bf16* __restrict__ vtw) {
    __shared__ __align__(16) bf16 smA[2][256 * 32];
    __shared__ __align__(16) bf16 smB[2][128 * 32];

    const int K = 1024;
    // grid (24,32)=768; XCD = flat&7 -> (bx half, by quarter) 2D chunk.
    const int flat = blockIdx.y * 24 + blockIdx.x;
    const int xcd = flat & 7;
    const int li = flat >> 3;                 // 0..95 within XCD
    const int bx = (xcd & 1) * 12 + (li % 12);
    const int by = (xcd >> 1) * 8 + (li / 12);

    const bool isq = (bx < 8);
    const bf16* A = isq ? qbw : kbw;
    const bf16* BT = isq ? WqT : WkvT;
    const bf16* bias = isq ? bq : bkv;
    const int bn0 = (isq ? bx : bx - 8) * 128;
    const int bm0 = by * 256;

    const int tid = threadIdx.x;
    const int lane = tid & 63;
    const int wave = tid >> 6;      // 0..7
    const int lm = lane & 15;
    const int lq = lane >> 4;
    const int wm = (wave >> 1) * 64;   // 4 M-groups cover 256 rows
    const int wn = (wave & 1) * 64;    // 2 N-groups cover 128 cols

    // staging: A = 1024 slots (256 rows x 4 chunks), 2 per thread;
    //          B = 512 slots (128 rows x 4 chunks), 1 per thread.
    const int sA0 = wave * 64;
    const int sA1 = 512 + wave * 64;
    const int sB = wave * 64;
    const size_t gAofs0 = swz_gofs(sA0 + lane, K);
    const size_t gAofs1 = swz_gofs(sA1 + lane, K);
    const size_t gBofs = swz_gofs(sB + lane, K);
    const int rc = (lq ^ ((lm >> 1) & 3)) * 8;  // swizzled read-chunk offset

    const f32x4 z4 = {0.f, 0.f, 0.f, 0.f};
    f32x4 acc[4][4];
#pragma unroll
    for (int i = 0; i < 4; ++i)
#pragma unroll
        for (int j = 0; j < 4; ++j) acc[i][j] = z4;

    const bf16* gA0 = A + (size_t)bm0 * K;
    const bf16* gB0 = BT + (size_t)bn0 * K;

    auto stage = [&](int kt, int buf) {
        const bf16* gB = gB0 + kt * 32;
        const bf16* gA = gA0 + kt * 32;
        lds_cp16(gB + gBofs, &smB[buf][0] + (size_t)sB * 8);
        lds_cp16(gA + gAofs0, &smA[buf][0] + (size_t)sA0 * 8);
        lds_cp16(gA + gAofs1, &smA[buf][0] + (size_t)sA1 * 8);
    };

    stage(0, 0);

    for (int kt = 0; kt < 32; ++kt) {
        if (kt + 1 < 32) {
            stage(kt + 1, (kt + 1) & 1);
            asm volatile("s_waitcnt vmcnt(3)" ::: "memory");
        } else {
            asm volatile("s_waitcnt vmcnt(0)" ::: "memory");
        }
        __builtin_amdgcn_s_barrier();

        const int cur = kt & 1;
        s16x8 af[4], bfr[4];
#pragma unroll
        for (int i = 0; i < 4; ++i) {
            af[i] = *(const s16x8*)(&smA[cur][0] + (wm + i * 16 + lm) * 32 + rc);
            bfr[i] =
                *(const s16x8*)(&smB[cur][0] + (wn + i * 16 + lm) * 32 + rc);
        }
#pragma unroll
        for (int i = 0; i < 4; ++i)
#pragma unroll
            for (int j = 0; j < 4; ++j)
                acc[i][j] = MFMA16(af[i], bfr[j], acc[i][j]);

        __builtin_amdgcn_s_barrier();  // readers done before buf overwrite
    }

#pragma unroll
    for (int j = 0; j < 4; ++j) {
        const int n = bn0 + wn + j * 16 + lm;
        const float bv = __bfloat162float(bias[n]);
        const bool dorope = isq || n < 1024;   // uniform per (wave,j)
        const int hd0 = n & 63;
        const int p = hd0 >> 1;
#pragma unroll
        for (int i = 0; i < 4; ++i) {
#pragma unroll
            for (int r = 0; r < 4; ++r) {
                const int m = bm0 + wm + i * 16 + lq * 4 + r;
                float v = acc[i][j][r] + bv;
                const int b = m >> 11, l = m & 2047;
                if (dorope) {
                    // partner lane holds the other element of the rope pair
                    float vo = __shfl_xor(v, 1, 64);
                    unsigned sc = ((const unsigned*)ropec)[l * 32 + p];
                    float sn = __uint_as_float(sc << 16);
                    float cs = __uint_as_float(sc & 0xffff0000u);
                    v = (hd0 & 1) ? (vo * sn + v * cs) : (v * cs - vo * sn);
                }
                if (isq) {
                    const int h = n >> 6, hd = n & 63;
                    qw[(((size_t)(b * 16 + h) * 2048) + l) * 64 + hd] =
                        __float2bfloat16(v * SCALE_LOG2E);
                } else if (n >= 1024) {
                    const int n2 = n - 1024;
                    const int h = n2 >> 6, hd = n2 & 63;
                    vtw[(((size_t)(b * 16 + h) * 64) + hd) * 2048 + l] =
                        __float2bfloat16(v);
                } else {
                    const int h = n >> 6, hd = n & 63;
                    kw[(((size_t)(b * 16 + h) * 2048) + l) * 64 + hd] =
                        __float2bfloat16(v);
                }
            }
        }
    }
}

// ---------------------------------------------------------------------------
// Causal attention, swapped-QK^T in-register softmax (no P LDS round-trip).
// Q pre-scaled by SCALE*log2(e) -> softmax is a bare exp2.
// lsum computed ON THE MATRIX PIPE (all-ones B fragment MFMA per tile).
// KVBLK=64 (2 sub-tiles of 32 per interval); pair {i,31-i} equalizes work.
// 2-buffer COUNTED-vmcnt(4) pipeline. V chunk-XOR swizzled; K rows PERMUTED
// at fragment load. Softmax without online max. setprio kept (helps attn,
// m191; unlike the GEMMs its MFMA operands come from registers, so no
// read->MFMA fence effect). (unchanged from R13)
// ---------------------------------------------------------------------------
__global__ __launch_bounds__(256) void attn_causal(
    const bf16* __restrict__ Q, const bf16* __restrict__ Kc,
    const bf16* __restrict__ VT, bf16* __restrict__ O) {
    __shared__ __align__(16) bf16 smK[2][4096];  // 2 subtiles [32 r][64 d] swz
    __shared__ __align__(16) bf16 smV[2][4096];  // 2 subtiles [64 hd][32 k] swz

    const int tid = threadIdx.x;
    const int lane = tid & 63;
    const int wave = tid >> 6;
    const int lm = lane & 15;
    const int lq = lane >> 4;

    // grid (16,64)=1024 blocks; XCD k gets bh in [k*8, k*8+8)
    const int flat = blockIdx.y * 16 + blockIdx.x;
    const int nfl = (flat & 7) * 128 + (flat >> 3);
    const int bxs = nfl & 15;
    const int bh = nfl >> 4;

    const int qbA = bxs * 64;          // short tile (few keys)
    const int qbB = (31 - bxs) * 64;   // long tile (many keys)
    const int qA0 = qbA + wave * 16;
    const int qB0 = qbB + wave * 16;

    const bf16* qp = Q + (size_t)bh * 2048 * 64;
    const bf16* kp = Kc + (size_t)bh * 2048 * 64;
    const bf16* vp = VT + (size_t)bh * 64 * 2048;

    // Q fragments (mfma B operand): n=qrow=lane&15, k=lq*8+j
    s16x8 aqA0 = *(const s16x8*)(qp + (size_t)(qA0 + lm) * 64 + lq * 8);
    s16x8 aqA1 = *(const s16x8*)(qp + (size_t)(qA0 + lm) * 64 + 32 + lq * 8);
    s16x8 aqB0 = *(const s16x8*)(qp + (size_t)(qB0 + lm) * 64 + lq * 8);
    s16x8 aqB1 = *(const s16x8*)(qp + (size_t)(qB0 + lm) * 64 + 32 + lq * 8);

    // all-ones bf16 B fragment for the lsum MFMA
    s16x8 ones;
#pragma unroll
    for (int i = 0; i < 8; ++i) ones[i] = (short)0x3F80;

    const f32x4 z4 = {0.f, 0.f, 0.f, 0.f};
    f32x4 oA[4], oB[4], lsA, lsB;
#pragma unroll
    for (int c = 0; c < 4; ++c) { oA[c] = z4; oB[c] = z4; }
    lsA = z4; lsB = z4;

    const int nitA = bxs + 1;        // A consumes chunks [0, nitA)
    const int nit = 33 - nitA;       // B consumes chunks [0, nit); 17..32

    // ---- cooperative staging (per 32-key sub-tile; wave does 1KB each) ----
    const int krow = wave * 8 + (lane >> 3);
    const int kcd = (lane & 7) ^ ((lane >> 3) & 3) ^ ((wave & 1) << 2);
    const int vrow = wave * 16 + (lane >> 2);
    const int vck = (lane & 3) ^ ((lane >> 4) & 3);

    // stage 64-key chunk starting at key kb into buffer buf
    auto stage = [&](int kb, int buf) {
        lds_cp16(kp + (size_t)(kb + krow) * 64 + kcd * 8,
                 &smK[buf][0] + wave * 512);
        lds_cp16(kp + (size_t)(kb + 32 + krow) * 64 + kcd * 8,
                 &smK[buf][0] + 2048 + wave * 512);
        lds_cp16(vp + (size_t)vrow * 2048 + kb + vck * 8,
                 &smV[buf][0] + wave * 512);
        lds_cp16(vp + (size_t)vrow * 2048 + kb + 32 + vck * 8,
                 &smV[buf][0] + 2048 + wave * 512);
    };

    stage(0, 0);

    const int rowgA = qA0 + lm;  // this lane's q-row (tile A)
    const int rowgB = qB0 + lm;  // this lane's q-row (tile B)
    const int lq4 = lq * 4;
    const int lq8 = lq * 8;

    // permuted K fragment row + its swizzle key
    const int pr = 8 * (lm >> 2) + (lm & 3);
    const int fk = (lm & 3) | (((lm >> 2) & 1) << 2);
    const int c0 = ((lq ^ fk) * 8);        // phys chunk offset, d-lo
    const int c1 = (((lq ^ 4) ^ fk) * 8);  // phys chunk offset, d-hi
    const int vc = (lq ^ (lm >> 2)) * 8;   // V phys chunk offset

    for (int it = 0; it < nit; ++it) {
        const int kb = it * 64;
        const int buf = it & 1;
        const bool doA = (it < nitA);

        if (it + 1 < nit) {
            stage(kb + 64, buf ^ 1);
            asm volatile("s_waitcnt vmcnt(4)" ::: "memory");
        } else {
            asm volatile("s_waitcnt vmcnt(0)" ::: "memory");
        }
        __builtin_amdgcn_s_barrier();

#pragma unroll
        for (int s = 0; s < 2; ++s) {
            const int kbs = kb + s * 32;
            const bf16* tK = &smK[buf][0] + s * 2048;
            const bf16* tV = &smV[buf][0] + s * 2048;

            // K fragments (A operand), permuted rows, from swizzled LDS
            s16x8 b00 = *(const s16x8*)(tK + pr * 64 + c0);
            s16x8 b01 = *(const s16x8*)(tK + pr * 64 + c1);
            s16x8 b10 = *(const s16x8*)(tK + (pr + 4) * 64 + c0);
            s16x8 b11 = *(const s16x8*)(tK + (pr + 4) * 64 + c1);
            s16x8 bv[4];
#pragma unroll
            for (int c = 0; c < 4; ++c)
                bv[c] = *(const s16x8*)(tV + (c * 16 + lm) * 32 + vc);

            // swapped QK^T: S^T row lq4+r = key {8lq+r | 8lq+4+r}
            f32x4 sB0 = z4, sB1 = z4, sA0 = z4, sA1 = z4;
            __builtin_amdgcn_s_setprio(1);
            sB0 = MFMA16(b00, aqB0, sB0);
            sB0 = MFMA16(b01, aqB1, sB0);
            sB1 = MFMA16(b10, aqB0, sB1);
            sB1 = MFMA16(b11, aqB1, sB1);
            if (doA) {
                sA0 = MFMA16(b00, aqA0, sA0);
                sA0 = MFMA16(b01, aqA1, sA0);
                sA1 = MFMA16(b10, aqA0, sA1);
                sA1 = MFMA16(b11, aqA1, sA1);
            }
            __builtin_amdgcn_s_setprio(0);

            // exp2 in-register -> PV A-fragment (Q pre-scaled)
            bf16 pbB[8];
            if (kbs + 31 <= qB0) {  // interior: no masking (wave-uniform)
#pragma unroll
                for (int r = 0; r < 4; ++r) {
                    pbB[r] = __float2bfloat16(exp2f(sB0[r]));
                    pbB[4 + r] = __float2bfloat16(exp2f(sB1[r]));
                }
            } else {
#pragma unroll
                for (int r = 0; r < 4; ++r) {
                    float p0 = (kbs + lq8 + r <= rowgB) ? exp2f(sB0[r]) : 0.f;
                    float p1 =
                        (kbs + lq8 + 4 + r <= rowgB) ? exp2f(sB1[r]) : 0.f;
                    pbB[r] = __float2bfloat16(p0);
                    pbB[4 + r] = __float2bfloat16(p1);
                }
            }
            s16x8 paB = *(const s16x8*)pbB;
            __builtin_amdgcn_s_setprio(1);
            oB[0] = MFMA16(paB, bv[0], oB[0]);
            oB[1] = MFMA16(paB, bv[1], oB[1]);
            oB[2] = MFMA16(paB, bv[2], oB[2]);
            oB[3] = MFMA16(paB, bv[3], oB[3]);
            lsB = MFMA16(paB, ones, lsB);
            __builtin_amdgcn_s_setprio(0);

            if (doA) {
                bf16 pbA[8];
                if (kbs + 31 <= qA0) {
#pragma unroll
                    for (int r = 0; r < 4; ++r) {
                        pbA[r] = __float2bfloat16(exp2f(sA0[r]));
                        pbA[4 + r] = __float2bfloat16(exp2f(sA1[r]));
                    }
                } else {
#pragma unroll
                    for (int r = 0; r < 4; ++r) {
                        float p0 =
                            (kbs + lq8 + r <= rowgA) ? exp2f(sA0[r]) : 0.f;
                        float p1 =
                            (kbs + lq8 + 4 + r <= rowgA) ? exp2f(sA1[r]) : 0.f;
                        pbA[r] = __float2bfloat16(p0);
                        pbA[4 + r] = __float2bfloat16(p1);
                    }
                }
                s16x8 paA = *(const s16x8*)pbA;
                __builtin_amdgcn_s_setprio(1);
                oA[0] = MFMA16(paA, bv[0], oA[0]);
                oA[1] = MFMA16(paA, bv[1], oA[1]);
                oA[2] = MFMA16(paA, bv[2], oA[2]);
                oA[3] = MFMA16(paA, bv[3], oA[3]);
                lsA = MFMA16(paA, ones, lsA);
                __builtin_amdgcn_s_setprio(0);
            }
        }

        __builtin_amdgcn_s_barrier();  // readers done before buf overwrite
    }

    // lsA/lsB C-layout == o C-layout: row lq4+r holds that q-row's sum in
    // every column -> divide directly, no cross-lane reduction needed.
    const int b = bh >> 4, h = bh & 15;
#pragma unroll
    for (int c = 0; c < 4; ++c) {
#pragma unroll
        for (int r = 0; r < 4; ++r) {
            const int hd = c * 16 + lm;
            const int lA = qA0 + lq4 + r;
            O[((size_t)(b * 2048 + lA)) * 1024 + h * 64 + hd] =
                __float2bfloat16(oA[c][r] / lsA[r]);
            const int lB = qB0 + lq4 + r;
            O[((size_t)(b * 2048 + lB)) * 1024 + h * 64 + hd] =
                __float2bfloat16(oB[c][r] / lsB[r]);
        }
    }
}

// ---------------------------------------------------------------------------
extern "C" void kernel_launch(void* const* d_in, const int* in_sizes, int n_in,
                              void* d_out, int out_size, void* d_ws,
                              size_t ws_size, hipStream_t stream) {
    // Inputs are f32; output is read by the harness as FLOAT32.
    const float* q_in = (const float*)d_in[0];
    const float* k_in = (const float*)d_in[1];
    // d_in[2] v_in unused by reference; d_in[3] mask: causal by construction
    const float* rope = (const float*)d_in[4];
    const float* Wq = (const float*)d_in[5];
    const float* bq = (const float*)d_in[6];
    const float* Wkv = (const float*)d_in[7];
    const float* bkv = (const float*)d_in[8];
    const float* Wp = (const float*)d_in[9];
    const float* bp = (const float*)d_in[10];
    float* out = (float*)d_out;

    char* ws = (char*)d_ws;
    bf16* bqc = (bf16*)ws;   ws += 2048;
    bf16* bkvc = (bf16*)ws;  ws += 4096;
    bf16* bpc = (bf16*)ws;   ws += 2048;
    bf16* ropec = (bf16*)ws; ws += 262144;
    bf16* WqT = (bf16*)ws;   ws += 2097152;
    bf16* WkvT = (bf16*)ws;  ws += 4194304;
    bf16* WpT = (bf16*)ws;   ws += 2097152;
    bf16* qw = (bf16*)ws;    ws += 16777216;   // [B,H,L,64] (pre-scaled)
    bf16* kw = (bf16*)ws;    ws += 16777216;   // [B,H,L,64]
    bf16* vtw = (bf16*)ws;   ws += 16777216;   // [B,H,64,L]
    bf16* aw = (bf16*)ws;    ws += 16777216;   // [B,L,1024]

    // Scratch aliasing (zero extra workspace):
    //   qbw = aw   (aw is only written later, by attn_causal)
    //   kbw = out  (out is only written later, by gemm_out)
    bf16* qbw = aw;
    bf16* kbw = (bf16*)out;

    dim3 blk(256);

    prep_fused<<<12354, blk, 0, stream>>>(q_in, k_in, rope, bq, bkv, bp, Wq,
                                          Wkv, Wp, qbw, kbw, ropec, bqc, bkvc,
                                          bpc, WqT, WkvT, WpT);

    gemm_qkv<<<dim3(24, 32), dim3(512), 0, stream>>>(qbw, kbw, WqT, WkvT, bqc,
                                                     bkvc, ropec, qw, kw, vtw);

    attn_causal<<<dim3(16, 64), blk, 0, stream>>>(qw, kw, vtw, aw);

    gemm_out<<<dim3(8, 64), blk, 0, stream>>>(aw, WpT, bpc, out, 8192, 1024,
                                              1024);
}